// Round 4
// baseline (819.991 us; speedup 1.0000x reference)
//
#include <hip/hip_runtime.h>
#include <math.h>

// ---------------------------------------------------------------------------
// SwinTransformerBlock3D  (B=2, D=16, H=56, W=56, C=256, heads=8, ws=4, ss=2)
// Inputs f32 (round-3 NaN proved bf16 misread), OUTPUT f32 (round-1/2 7.6875
// == sqrt(2)*max|x| proved the harness reads d_out as f32).
// M = 100352 rows, n=64 tokens/window, 1568 windows. Chunked (4 x 25088 rows).
//   loop1 per chunk: LN1+roll+partition -> qkv GEMM -> attention -> proj GEMM
//                    (+window reverse + roll + residual(x)) -> x1 == d_out(f32)
//   loop2 per chunk: LN2(d_out) -> fc1+GELU -> fc2 + residual -> d_out (f32)
// ---------------------------------------------------------------------------

using f32x4  = __attribute__((ext_vector_type(4))) float;
using bf16x8 = __attribute__((ext_vector_type(8))) short;

#define M_CHUNK 25088
#define W_CHUNK 392
#define NCHUNK  4

__device__ __forceinline__ short f2bf(float f) {
  unsigned u = __builtin_bit_cast(unsigned, f);
  u += 0x7fffu + ((u >> 16) & 1u);          // RNE
  return (short)(u >> 16);
}
__device__ __forceinline__ float bf2f(short s) {
  return __builtin_bit_cast(float, ((unsigned)(unsigned short)s) << 16);
}

// ---------------------------------------------------------------------------
// weight cast + transpose: in [K][N] f32 -> out [N][K] bf16
__global__ void cast_transpose_k(const float* __restrict__ in,
                                 short* __restrict__ out, int K, int N) {
  const int idx = blockIdx.x * 256 + threadIdx.x;
  const int k = idx / N, n = idx % N;
  out[(size_t)n * K + k] = f2bf(in[idx]);
}

// ---------------------------------------------------------------------------
// LN1 + roll(-2) + window partition.  One wave per row; chunk-local output.
__global__ __launch_bounds__(256) void ln1_part_k(
    const float* __restrict__ x, const float* __restrict__ g,
    const float* __restrict__ bta, short* __restrict__ xw, int row0) {
  const int wave = threadIdx.x >> 6, lane = threadIdx.x & 63;
  const int lr = blockIdx.x * 4 + wave;
  const int row = row0 + lr;
  const int win = row >> 6, tok = row & 63;
  const int b = win / 784, wi = win % 784;
  const int wd = wi / 196, wh = (wi / 14) % 14, ww = wi % 14;
  const int tz = tok >> 4, ty = (tok >> 2) & 3, tx = tok & 3;
  const int gd = (wd * 4 + tz + 2) & 15;
  int gh = wh * 4 + ty + 2; if (gh >= 56) gh -= 56;
  int gw = ww * 4 + tx + 2; if (gw >= 56) gw -= 56;
  const size_t src = ((((size_t)b * 16 + gd) * 56 + gh) * 56 + gw) * 256;
  const float4 v = ((const float4*)(x + src))[lane];
  float s = v.x + v.y + v.z + v.w;
#pragma unroll
  for (int m = 1; m < 64; m <<= 1) s += __shfl_xor(s, m);
  const float mean = s * (1.f / 256.f);
  const float dx = v.x - mean, dy = v.y - mean, dz = v.z - mean, dw = v.w - mean;
  float q = dx * dx + dy * dy + dz * dz + dw * dw;
#pragma unroll
  for (int m = 1; m < 64; m <<= 1) q += __shfl_xor(q, m);
  const float rstd = rsqrtf(q * (1.f / 256.f) + 1e-5f);
  const float4 gg = ((const float4*)g)[lane];
  const float4 bb = ((const float4*)bta)[lane];
  short4 o;
  o.x = f2bf(dx * rstd * gg.x + bb.x);
  o.y = f2bf(dy * rstd * gg.y + bb.y);
  o.z = f2bf(dz * rstd * gg.z + bb.z);
  o.w = f2bf(dw * rstd * gg.w + bb.w);
  *(short4*)(xw + (size_t)lr * 256 + lane * 4) = o;
}

// LN2: reads f32 x1 (== d_out, global rows), writes chunk-local bf16 yn
__global__ __launch_bounds__(256) void ln2_k(
    const float* __restrict__ x1, const float* __restrict__ g,
    const float* __restrict__ bta, short* __restrict__ yn, int row0) {
  const int wave = threadIdx.x >> 6, lane = threadIdx.x & 63;
  const int lr = blockIdx.x * 4 + wave;
  const float4 v = ((const float4*)(x1 + (size_t)(row0 + lr) * 256))[lane];
  float s = v.x + v.y + v.z + v.w;
#pragma unroll
  for (int m = 1; m < 64; m <<= 1) s += __shfl_xor(s, m);
  const float mean = s * (1.f / 256.f);
  const float dx = v.x - mean, dy = v.y - mean, dz = v.z - mean, dw = v.w - mean;
  float q = dx * dx + dy * dy + dz * dz + dw * dw;
#pragma unroll
  for (int m = 1; m < 64; m <<= 1) q += __shfl_xor(q, m);
  const float rstd = rsqrtf(q * (1.f / 256.f) + 1e-5f);
  const float4 gg = ((const float4*)g)[lane];
  const float4 bb = ((const float4*)bta)[lane];
  short4 o;
  o.x = f2bf(dx * rstd * gg.x + bb.x);
  o.y = f2bf(dy * rstd * gg.y + bb.y);
  o.z = f2bf(dz * rstd * gg.z + bb.z);
  o.w = f2bf(dw * rstd * gg.w + bb.w);
  *(short4*)(yn + (size_t)lr * 256 + lane * 4) = o;
}

// ---------------------------------------------------------------------------
// bf16 MFMA GEMM: C[Mc,N] = A[Mc,K] * Bt[N,K]^T + bias. 128x128 tile, BK=64.
// EPI: 0=bf16 store, 1=bf16 GELU store,
//      2=f32 swin-reverse+roll+resid(x f32) scatter -> x1/d_out (global rows)
//      3=f32 +resid(x1 f32, pre-offset) -> d_out (pre-offset, in-place ok)
template <int EPI>
__global__ __launch_bounds__(256) void gemm_k(
    const short* __restrict__ A, const short* __restrict__ Bt,
    const float* __restrict__ bias, const void* __restrict__ resid,
    void* __restrict__ OutP, int N, int K, int row0) {
  __shared__ short As[128 * 72];
  __shared__ short Bs[128 * 72];
  const int tid = threadIdx.x;
  const int wave = tid >> 6, lane = tid & 63;
  const int quad = lane >> 4, l15 = lane & 15;
  const int m0 = blockIdx.y * 128;
  const int n0 = blockIdx.x * 128;
  const int wm = (wave >> 1) * 64, wn = (wave & 1) * 64;
  const int p_base = wave * 256;

  f32x4 acc[4][4] = {};

  for (int k0 = 0; k0 < K; k0 += 64) {
    bf16x8 va[4], vb[4];
#pragma unroll
    for (int i = 0; i < 4; ++i) {
      const int p = p_base + i * 64 + lane;
      const int row = p >> 3, c = p & 7;
      va[i] = *(const bf16x8*)(A  + (size_t)(m0 + row) * K + (k0 + c * 8));
      vb[i] = *(const bf16x8*)(Bt + (size_t)(n0 + row) * K + (k0 + c * 8));
    }
    __syncthreads();
#pragma unroll
    for (int i = 0; i < 4; ++i) {
      const int p = p_base + i * 64 + lane;
      const int row = p >> 3, c = p & 7;
      *(bf16x8*)(As + row * 72 + c * 8) = va[i];
      *(bf16x8*)(Bs + row * 72 + c * 8) = vb[i];
    }
    __syncthreads();
#pragma unroll
    for (int ks = 0; ks < 2; ++ks) {
      bf16x8 af[4], bfr[4];
#pragma unroll
      for (int t = 0; t < 4; ++t) {
        af[t]  = *(const bf16x8*)(As + (wm + t * 16 + l15) * 72 + (ks * 4 + quad) * 8);
        bfr[t] = *(const bf16x8*)(Bs + (wn + t * 16 + l15) * 72 + (ks * 4 + quad) * 8);
      }
#pragma unroll
      for (int mt = 0; mt < 4; ++mt)
#pragma unroll
        for (int nt = 0; nt < 4; ++nt)
          acc[mt][nt] = __builtin_amdgcn_mfma_f32_16x16x32_bf16(
              af[mt], bfr[nt], acc[mt][nt], 0, 0, 0);
    }
  }

  // epilogue; C/D layout: row=quad*4+reg, col=l15  [m89/m91 verified]
  if constexpr (EPI == 0 || EPI == 1) {
    short* out = (short*)OutP;
#pragma unroll
    for (int nt = 0; nt < 4; ++nt) {
      const int col = n0 + wn + nt * 16 + l15;
      const float bv = bias[col];
#pragma unroll
      for (int mt = 0; mt < 4; ++mt)
#pragma unroll
        for (int reg = 0; reg < 4; ++reg) {
          const int row = m0 + wm + mt * 16 + quad * 4 + reg;
          float v = acc[mt][nt][reg] + bv;
          if constexpr (EPI == 1)
            v = 0.5f * v * (1.f + erff(v * 0.70710678118654752f));
          out[(size_t)row * N + col] = f2bf(v);
        }
    }
  } else if constexpr (EPI == 2) {
    float* out = (float*)OutP;                 // x1 == d_out, f32 global rows
    const float* rs = (const float*)resid;     // x, f32, global rows
#pragma unroll
    for (int nt = 0; nt < 4; ++nt) {
      const int col = n0 + wn + nt * 16 + l15;
      const float bv = bias[col];
#pragma unroll
      for (int mt = 0; mt < 4; ++mt)
#pragma unroll
        for (int reg = 0; reg < 4; ++reg) {
          const int row = row0 + m0 + wm + mt * 16 + quad * 4 + reg;
          const int win = row >> 6, tok = row & 63;
          const int b = win / 784, wi = win % 784;
          const int wd = wi / 196, wh = (wi / 14) % 14, ww = wi % 14;
          const int tz = tok >> 4, ty = (tok >> 2) & 3, tx = tok & 3;
          const int gd = (wd * 4 + tz + 2) & 15;
          int gh = wh * 4 + ty + 2; if (gh >= 56) gh -= 56;
          int gw = ww * 4 + tx + 2; if (gw >= 56) gw -= 56;
          const size_t dst =
              ((((size_t)b * 16 + gd) * 56 + gh) * 56 + gw) * 256 + col;
          out[dst] = rs[dst] + acc[mt][nt][reg] + bv;
        }
    }
  } else {
    float* out = (float*)OutP;                 // d_out + row0*256 (f32)
    const float* rs = (const float*)resid;     // x1 == same buffer, pre-offset
#pragma unroll
    for (int nt = 0; nt < 4; ++nt) {
      const int col = n0 + wn + nt * 16 + l15;
      const float bv = bias[col];
#pragma unroll
      for (int mt = 0; mt < 4; ++mt)
#pragma unroll
        for (int reg = 0; reg < 4; ++reg) {
          const int row = m0 + wm + mt * 16 + quad * 4 + reg;
          const float v = rs[(size_t)row * 256 + col] +
                          acc[mt][nt][reg] + bv;
          out[(size_t)row * 256 + col] = v;
        }
    }
  }
}

// ---------------------------------------------------------------------------
// Windowed attention. grid = W_CHUNK*2 blocks; 4 waves, 1 head/wave.
__global__ __launch_bounds__(256) void attn_k(
    const short* __restrict__ qkv, const float* __restrict__ rpb,
    short* __restrict__ aout, int win0) {
  __shared__ short Plds[4 * 64 * 80];
  const int tid = threadIdx.x;
  const int wave = tid >> 6, lane = tid & 63;
  const int quad = lane >> 4, l15 = lane & 15;
  const int wl = blockIdx.x >> 1;                 // chunk-local window
  const int h = ((blockIdx.x & 1) << 2) + wave;
  const int wi = (win0 + wl) % 784;               // window-in-batch for mask
  const int wd = wi / 196, wh = (wi / 14) % 14, ww = wi % 14;
  const short* base = qkv + (size_t)wl * (64 * 768);

  // Q,K fragments: A[m=l15][k=quad*8+j], B[k=quad*8+j][n=l15]
  bf16x8 qf[4], kf[4];
#pragma unroll
  for (int t = 0; t < 4; ++t) {
    const short* qp = base + (size_t)(t * 16 + l15) * 768 + h * 32 + quad * 8;
    qf[t] = *(const bf16x8*)qp;
    kf[t] = *(const bf16x8*)(qp + 256);
  }
  f32x4 S[4][4] = {};
#pragma unroll
  for (int mt = 0; mt < 4; ++mt)
#pragma unroll
    for (int nt = 0; nt < 4; ++nt)
      S[mt][nt] = __builtin_amdgcn_mfma_f32_16x16x32_bf16(
          qf[mt], kf[nt], S[mt][nt], 0, 0, 0);

  const bool bd = (wd == 3), bh = (wh == 13), bw = (ww == 13);
  const int yc = l15 >> 2, xc = l15 & 3;
  int labc[4];
#pragma unroll
  for (int nt = 0; nt < 4; ++nt) {
    const int rd = bd ? (nt < 2 ? 1 : 2) : 0;
    const int rh = bh ? (yc < 2 ? 1 : 2) : 0;
    const int rw = bw ? (xc < 2 ? 1 : 2) : 0;
    labc[nt] = rd * 9 + rh * 3 + rw;
  }
  const float scale = 0.17677669529663687f;   // 32^-0.5
#pragma unroll
  for (int mt = 0; mt < 4; ++mt) {
    const int rdr = bd ? (mt < 2 ? 1 : 2) : 0;
    const int rhr = bh ? (quad < 2 ? 1 : 2) : 0;
#pragma unroll
    for (int reg = 0; reg < 4; ++reg) {
      const int rwr = bw ? (reg < 2 ? 1 : 2) : 0;
      const int labr = rdr * 9 + rhr * 3 + rwr;
      float sc[4];
#pragma unroll
      for (int nt = 0; nt < 4; ++nt) {
        const int rpi = (mt - nt + 3) * 49 + (quad - yc + 3) * 7 + (reg - xc + 3);
        const float bias = rpb[rpi * 8 + h];
        const float mv = (labr == labc[nt]) ? 0.f : -100.f;
        sc[nt] = S[mt][nt][reg] * scale + bias + mv;
      }
      float mx = fmaxf(fmaxf(sc[0], sc[1]), fmaxf(sc[2], sc[3]));
      mx = fmaxf(mx, __shfl_xor(mx, 1));
      mx = fmaxf(mx, __shfl_xor(mx, 2));
      mx = fmaxf(mx, __shfl_xor(mx, 4));
      mx = fmaxf(mx, __shfl_xor(mx, 8));
      float p[4], sum = 0.f;
#pragma unroll
      for (int nt = 0; nt < 4; ++nt) { p[nt] = __expf(sc[nt] - mx); sum += p[nt]; }
      sum += __shfl_xor(sum, 1);
      sum += __shfl_xor(sum, 2);
      sum += __shfl_xor(sum, 4);
      sum += __shfl_xor(sum, 8);
      const float inv = 1.f / sum;
      const int r = mt * 16 + quad * 4 + reg;
#pragma unroll
      for (int nt = 0; nt < 4; ++nt)
        Plds[(wave * 64 + r) * 80 + nt * 16 + l15] = f2bf(p[nt] * inv);
    }
  }

  bf16x8 vf[2][2];
#pragma unroll
  for (int kt = 0; kt < 2; ++kt)
#pragma unroll
    for (int n2 = 0; n2 < 2; ++n2)
#pragma unroll
      for (int j = 0; j < 8; ++j)
        vf[kt][n2][j] =
            base[(size_t)(kt * 32 + quad * 8 + j) * 768 + 512 + h * 32 + n2 * 16 + l15];

  f32x4 O[4][2] = {};
#pragma unroll
  for (int mt = 0; mt < 4; ++mt) {
    const short* pr = &Plds[(wave * 64 + mt * 16 + l15) * 80 + quad * 8];
    const bf16x8 pa0 = *(const bf16x8*)pr;
    const bf16x8 pa1 = *(const bf16x8*)(pr + 32);
#pragma unroll
    for (int n2 = 0; n2 < 2; ++n2) {
      O[mt][n2] = __builtin_amdgcn_mfma_f32_16x16x32_bf16(pa0, vf[0][n2], O[mt][n2], 0, 0, 0);
      O[mt][n2] = __builtin_amdgcn_mfma_f32_16x16x32_bf16(pa1, vf[1][n2], O[mt][n2], 0, 0, 0);
    }
  }
#pragma unroll
  for (int mt = 0; mt < 4; ++mt)
#pragma unroll
    for (int n2 = 0; n2 < 2; ++n2)
#pragma unroll
      for (int reg = 0; reg < 4; ++reg) {
        const int tok = mt * 16 + quad * 4 + reg;
        aout[((size_t)wl * 64 + tok) * 256 + h * 32 + n2 * 16 + l15] =
            f2bf(O[mt][n2][reg]);
      }
}

// ---------------------------------------------------------------------------
extern "C" void kernel_launch(void* const* d_in, const int* in_sizes, int n_in,
                              void* d_out, int out_size, void* d_ws,
                              size_t ws_size, hipStream_t stream) {
  const float* x      = (const float*)d_in[0];
  const float* n1g    = (const float*)d_in[1];
  const float* n1b    = (const float*)d_in[2];
  const float* qkv_w  = (const float*)d_in[3];
  const float* qkv_b  = (const float*)d_in[4];
  const float* proj_w = (const float*)d_in[5];
  const float* proj_b = (const float*)d_in[6];
  const float* rpb    = (const float*)d_in[7];
  const float* n2g    = (const float*)d_in[8];
  const float* n2b    = (const float*)d_in[9];
  const float* fc1_w  = (const float*)d_in[10];
  const float* fc1_b  = (const float*)d_in[11];
  const float* fc2_w  = (const float*)d_in[12];
  const float* fc2_b  = (const float*)d_in[13];

  char* ws = (char*)d_ws;
  short* wt_qkv  = (short*)(ws + 0);          //    393,216 B
  short* wt_proj = (short*)(ws + 393216);     //    131,072 B
  short* wt_fc1  = (short*)(ws + 524288);     //    524,288 B
  short* wt_fc2  = (short*)(ws + 1048576);    //    524,288 B
  short* bufS    = (short*)(ws + 1572864);    // 12,845,056 B (xw/ao/yn chunk)
  short* bufL    = (short*)(ws + 14417920);   // 51,380,224 B (qkv/h1 chunk)
  // total 65,798,144 B
  float* x1      = (float*)d_out;             // x1 lives in d_out (f32)

  cast_transpose_k<<<768, 256, 0, stream>>>(qkv_w, wt_qkv, 256, 768);
  cast_transpose_k<<<256, 256, 0, stream>>>(proj_w, wt_proj, 256, 256);
  cast_transpose_k<<<1024, 256, 0, stream>>>(fc1_w, wt_fc1, 256, 1024);
  cast_transpose_k<<<1024, 256, 0, stream>>>(fc2_w, wt_fc2, 1024, 256);

  for (int c = 0; c < NCHUNK; ++c) {
    const int row0 = c * M_CHUNK, win0 = c * W_CHUNK;
    ln1_part_k<<<M_CHUNK / 4, 256, 0, stream>>>(x, n1g, n1b, bufS, row0);
    gemm_k<0><<<dim3(6, M_CHUNK / 128), 256, 0, stream>>>(
        bufS, wt_qkv, qkv_b, nullptr, bufL, 768, 256, 0);
    attn_k<<<W_CHUNK * 2, 256, 0, stream>>>(bufL, rpb, bufS, win0);
    gemm_k<2><<<dim3(2, M_CHUNK / 128), 256, 0, stream>>>(
        bufS, wt_proj, proj_b, x, x1, 256, 256, row0);
  }
  for (int c = 0; c < NCHUNK; ++c) {
    const int row0 = c * M_CHUNK;
    ln2_k<<<M_CHUNK / 4, 256, 0, stream>>>(x1, n2g, n2b, bufS, row0);
    gemm_k<1><<<dim3(8, M_CHUNK / 128), 256, 0, stream>>>(
        bufS, wt_fc1, fc1_b, nullptr, bufL, 1024, 256, 0);
    gemm_k<3><<<dim3(2, M_CHUNK / 128), 256, 0, stream>>>(
        bufL, wt_fc2, fc2_b, x1 + (size_t)row0 * 256,
        x1 + (size_t)row0 * 256, 256, 1024, 0);
  }
}

// Round 5
// 732.191 us; speedup vs baseline: 1.1199x; 1.1199x over previous
//
#include <hip/hip_runtime.h>
#include <math.h>

// ---------------------------------------------------------------------------
// SwinTransformerBlock3D  (B=2, D=16, H=56, W=56, C=256, heads=8, ws=4, ss=2)
// f32 in / f32 out (established round 4). M = 100352 rows, 1568 windows.
// Unchunked (ws >= 360 MB per round-1 evidence), 8 launches:
//   transpose_all -> ln1+roll+partition -> qkv GEMM -> attention
//   -> proj GEMM(+reverse+roll+resid -> d_out f32) -> ln2
//   -> fc1 GEMM(+GELU) -> fc2 GEMM(+resid, in-place d_out)
// GEMM: 128x128 tile, BK=64, global_load_lds width=16 + XOR swizzle
// (m97 structure; validated correct in round 1 via identical-output evidence).
// ---------------------------------------------------------------------------

using f32x4  = __attribute__((ext_vector_type(4))) float;
using bf16x8 = __attribute__((ext_vector_type(8))) short;

__device__ __forceinline__ short f2bf(float f) {
  unsigned u = __builtin_bit_cast(unsigned, f);
  u += 0x7fffu + ((u >> 16) & 1u);          // RNE
  return (short)(u >> 16);
}

#define GLDS16(g, l) __builtin_amdgcn_global_load_lds(                        \
    (__attribute__((address_space(1))) void*)(g),                             \
    (__attribute__((address_space(3))) void*)(l), 16, 0, 0)

// ---------------------------------------------------------------------------
// all four weight transposes in one launch: [K][N] f32 -> [N][K] bf16
__global__ void transpose_all_k(const float* __restrict__ qkv_w,
                                const float* __restrict__ proj_w,
                                const float* __restrict__ fc1_w,
                                const float* __restrict__ fc2_w,
                                short* __restrict__ o_qkv,
                                short* __restrict__ o_proj,
                                short* __restrict__ o_fc1,
                                short* __restrict__ o_fc2) {
  int bid = blockIdx.x;
  const float* in; short* out; int K, N;
  if (bid < 768)       { in = qkv_w;  out = o_qkv;  K = 256;  N = 768; }
  else if (bid < 1024) { in = proj_w; out = o_proj; K = 256;  N = 256;  bid -= 768; }
  else if (bid < 2048) { in = fc1_w;  out = o_fc1;  K = 256;  N = 1024; bid -= 1024; }
  else                 { in = fc2_w;  out = o_fc2;  K = 1024; N = 256;  bid -= 2048; }
  const int idx = bid * 256 + threadIdx.x;
  const int k = idx / N, n = idx % N;
  out[(size_t)n * K + k] = f2bf(in[idx]);
}

// ---------------------------------------------------------------------------
// LN1 + roll(-2) + window partition.  One wave per output row.
__global__ __launch_bounds__(256) void ln1_part_k(
    const float* __restrict__ x, const float* __restrict__ g,
    const float* __restrict__ bta, short* __restrict__ xw) {
  const int wave = threadIdx.x >> 6, lane = threadIdx.x & 63;
  const int row = blockIdx.x * 4 + wave;
  const int win = row >> 6, tok = row & 63;
  const int b = win / 784, wi = win % 784;
  const int wd = wi / 196, wh = (wi / 14) % 14, ww = wi % 14;
  const int tz = tok >> 4, ty = (tok >> 2) & 3, tx = tok & 3;
  const int gd = (wd * 4 + tz + 2) & 15;
  int gh = wh * 4 + ty + 2; if (gh >= 56) gh -= 56;
  int gw = ww * 4 + tx + 2; if (gw >= 56) gw -= 56;
  const size_t src = ((((size_t)b * 16 + gd) * 56 + gh) * 56 + gw) * 256;
  const float4 v = ((const float4*)(x + src))[lane];
  float s = v.x + v.y + v.z + v.w;
#pragma unroll
  for (int m = 1; m < 64; m <<= 1) s += __shfl_xor(s, m);
  const float mean = s * (1.f / 256.f);
  const float dx = v.x - mean, dy = v.y - mean, dz = v.z - mean, dw = v.w - mean;
  float q = dx * dx + dy * dy + dz * dz + dw * dw;
#pragma unroll
  for (int m = 1; m < 64; m <<= 1) q += __shfl_xor(q, m);
  const float rstd = rsqrtf(q * (1.f / 256.f) + 1e-5f);
  const float4 gg = ((const float4*)g)[lane];
  const float4 bb = ((const float4*)bta)[lane];
  short4 o;
  o.x = f2bf(dx * rstd * gg.x + bb.x);
  o.y = f2bf(dy * rstd * gg.y + bb.y);
  o.z = f2bf(dz * rstd * gg.z + bb.z);
  o.w = f2bf(dw * rstd * gg.w + bb.w);
  *(short4*)(xw + (size_t)row * 256 + lane * 4) = o;
}

// LN2: reads f32 x1 (== d_out), writes bf16 yn
__global__ __launch_bounds__(256) void ln2_k(
    const float* __restrict__ x1, const float* __restrict__ g,
    const float* __restrict__ bta, short* __restrict__ yn) {
  const int wave = threadIdx.x >> 6, lane = threadIdx.x & 63;
  const int row = blockIdx.x * 4 + wave;
  const float4 v = ((const float4*)(x1 + (size_t)row * 256))[lane];
  float s = v.x + v.y + v.z + v.w;
#pragma unroll
  for (int m = 1; m < 64; m <<= 1) s += __shfl_xor(s, m);
  const float mean = s * (1.f / 256.f);
  const float dx = v.x - mean, dy = v.y - mean, dz = v.z - mean, dw = v.w - mean;
  float q = dx * dx + dy * dy + dz * dz + dw * dw;
#pragma unroll
  for (int m = 1; m < 64; m <<= 1) q += __shfl_xor(q, m);
  const float rstd = rsqrtf(q * (1.f / 256.f) + 1e-5f);
  const float4 gg = ((const float4*)g)[lane];
  const float4 bb = ((const float4*)bta)[lane];
  short4 o;
  o.x = f2bf(dx * rstd * gg.x + bb.x);
  o.y = f2bf(dy * rstd * gg.y + bb.y);
  o.z = f2bf(dz * rstd * gg.z + bb.z);
  o.w = f2bf(dw * rstd * gg.w + bb.w);
  *(short4*)(yn + (size_t)row * 256 + lane * 4) = o;
}

// ---------------------------------------------------------------------------
// bf16 MFMA GEMM: C[M,N] = A[M,K] * Bt[N,K]^T + bias. 128x128 tile, BK=64,
// global_load_lds width=16 + XOR swizzle (m97 structure).
// EPI: 0=bf16 store, 1=bf16 GELU store,
//      2=f32 swin-reverse+roll+resid(x f32) scatter -> d_out (global rows)
//      3=f32 +resid(f32) -> d_out (in-place)
template <int EPI>
__global__ __launch_bounds__(256) void gemm_k(
    const short* __restrict__ A, const short* __restrict__ Bt,
    const float* __restrict__ bias, const float* __restrict__ resid,
    void* __restrict__ OutP, int N, int K) {
  __shared__ short As[128 * 64];
  __shared__ short Bs[128 * 64];
  const int tid = threadIdx.x;
  const int wave = tid >> 6, lane = tid & 63;
  const int quad = lane >> 4, l15 = lane & 15;
  const int m0 = blockIdx.y * 128;
  const int n0 = blockIdx.x * 128;
  const int wm = (wave >> 1) * 64, wn = (wave & 1) * 64;

  f32x4 acc[4][4] = {};

  for (int k0 = 0; k0 < K; k0 += 64) {
    __syncthreads();
#pragma unroll
    for (int i = 0; i < 4; ++i) {
      const int p = wave * 256 + i * 64 + lane;
      const int row = p >> 3;
      const int c = (p & 7) ^ (row & 7);                 // XOR swizzle
      GLDS16(A  + (size_t)(m0 + row) * K + (k0 + c * 8),
             As + (size_t)(wave * 256 + i * 64) * 8);
      GLDS16(Bt + (size_t)(n0 + row) * K + (k0 + c * 8),
             Bs + (size_t)(wave * 256 + i * 64) * 8);
    }
    __syncthreads();
#pragma unroll
    for (int ks = 0; ks < 2; ++ks) {
      bf16x8 af[4], bfr[4];
#pragma unroll
      for (int t = 0; t < 4; ++t) {
        const int ra = wm + t * 16 + l15;
        const int ca = (ks * 4 + quad) ^ (ra & 7);
        af[t] = *(const bf16x8*)(As + ra * 64 + ca * 8);
        const int rb = wn + t * 16 + l15;
        const int cb = (ks * 4 + quad) ^ (rb & 7);
        bfr[t] = *(const bf16x8*)(Bs + rb * 64 + cb * 8);
      }
#pragma unroll
      for (int mt = 0; mt < 4; ++mt)
#pragma unroll
        for (int nt = 0; nt < 4; ++nt)
          acc[mt][nt] = __builtin_amdgcn_mfma_f32_16x16x32_bf16(
              af[mt], bfr[nt], acc[mt][nt], 0, 0, 0);
    }
  }

  // epilogue; C/D layout: row=quad*4+reg, col=l15  [m89/m91 verified]
  if constexpr (EPI == 0 || EPI == 1) {
    short* out = (short*)OutP;
#pragma unroll
    for (int nt = 0; nt < 4; ++nt) {
      const int col = n0 + wn + nt * 16 + l15;
      const float bv = bias[col];
#pragma unroll
      for (int mt = 0; mt < 4; ++mt)
#pragma unroll
        for (int reg = 0; reg < 4; ++reg) {
          const int row = m0 + wm + mt * 16 + quad * 4 + reg;
          float v = acc[mt][nt][reg] + bv;
          if constexpr (EPI == 1)
            v = 0.5f * v * (1.f + erff(v * 0.70710678118654752f));
          out[(size_t)row * N + col] = f2bf(v);
        }
    }
  } else if constexpr (EPI == 2) {
    float* out = (float*)OutP;                 // d_out, f32 global rows
#pragma unroll
    for (int nt = 0; nt < 4; ++nt) {
      const int col = n0 + wn + nt * 16 + l15;
      const float bv = bias[col];
#pragma unroll
      for (int mt = 0; mt < 4; ++mt)
#pragma unroll
        for (int reg = 0; reg < 4; ++reg) {
          const int row = m0 + wm + mt * 16 + quad * 4 + reg;
          const int win = row >> 6, tok = row & 63;
          const int b = win / 784, wi = win % 784;
          const int wd = wi / 196, wh = (wi / 14) % 14, ww = wi % 14;
          const int tz = tok >> 4, ty = (tok >> 2) & 3, tx = tok & 3;
          const int gd = (wd * 4 + tz + 2) & 15;
          int gh = wh * 4 + ty + 2; if (gh >= 56) gh -= 56;
          int gw = ww * 4 + tx + 2; if (gw >= 56) gw -= 56;
          const size_t dst =
              ((((size_t)b * 16 + gd) * 56 + gh) * 56 + gw) * 256 + col;
          out[dst] = resid[dst] + acc[mt][nt][reg] + bv;
        }
    }
  } else {
    float* out = (float*)OutP;                 // d_out (in-place resid)
#pragma unroll
    for (int nt = 0; nt < 4; ++nt) {
      const int col = n0 + wn + nt * 16 + l15;
      const float bv = bias[col];
#pragma unroll
      for (int mt = 0; mt < 4; ++mt)
#pragma unroll
        for (int reg = 0; reg < 4; ++reg) {
          const int row = m0 + wm + mt * 16 + quad * 4 + reg;
          out[(size_t)row * 256 + col] =
              resid[(size_t)row * 256 + col] + acc[mt][nt][reg] + bv;
        }
    }
  }
}

// ---------------------------------------------------------------------------
// Windowed attention. grid = 1568*2 blocks; 4 waves, 1 head/wave.
__global__ __launch_bounds__(256) void attn_k(
    const short* __restrict__ qkv, const float* __restrict__ rpb,
    short* __restrict__ aout) {
  __shared__ short Plds[4 * 64 * 80];
  const int tid = threadIdx.x;
  const int wave = tid >> 6, lane = tid & 63;
  const int quad = lane >> 4, l15 = lane & 15;
  const int win = blockIdx.x >> 1;
  const int h = ((blockIdx.x & 1) << 2) + wave;
  const int wi = win % 784;
  const int wd = wi / 196, wh = (wi / 14) % 14, ww = wi % 14;
  const short* base = qkv + (size_t)win * (64 * 768);

  // Q,K fragments: A[m=l15][k=quad*8+j], B[k=quad*8+j][n=l15]
  bf16x8 qf[4], kf[4];
#pragma unroll
  for (int t = 0; t < 4; ++t) {
    const short* qp = base + (size_t)(t * 16 + l15) * 768 + h * 32 + quad * 8;
    qf[t] = *(const bf16x8*)qp;
    kf[t] = *(const bf16x8*)(qp + 256);
  }
  f32x4 S[4][4] = {};
#pragma unroll
  for (int mt = 0; mt < 4; ++mt)
#pragma unroll
    for (int nt = 0; nt < 4; ++nt)
      S[mt][nt] = __builtin_amdgcn_mfma_f32_16x16x32_bf16(
          qf[mt], kf[nt], S[mt][nt], 0, 0, 0);

  const bool bd = (wd == 3), bh = (wh == 13), bw = (ww == 13);
  const int yc = l15 >> 2, xc = l15 & 3;
  int labc[4];
#pragma unroll
  for (int nt = 0; nt < 4; ++nt) {
    const int rd = bd ? (nt < 2 ? 1 : 2) : 0;
    const int rh = bh ? (yc < 2 ? 1 : 2) : 0;
    const int rw = bw ? (xc < 2 ? 1 : 2) : 0;
    labc[nt] = rd * 9 + rh * 3 + rw;
  }
  const float scale = 0.17677669529663687f;   // 32^-0.5
#pragma unroll
  for (int mt = 0; mt < 4; ++mt) {
    const int rdr = bd ? (mt < 2 ? 1 : 2) : 0;
    const int rhr = bh ? (quad < 2 ? 1 : 2) : 0;
#pragma unroll
    for (int reg = 0; reg < 4; ++reg) {
      const int rwr = bw ? (reg < 2 ? 1 : 2) : 0;
      const int labr = rdr * 9 + rhr * 3 + rwr;
      float sc[4];
#pragma unroll
      for (int nt = 0; nt < 4; ++nt) {
        const int rpi = (mt - nt + 3) * 49 + (quad - yc + 3) * 7 + (reg - xc + 3);
        const float bias = rpb[rpi * 8 + h];
        const float mv = (labr == labc[nt]) ? 0.f : -100.f;
        sc[nt] = S[mt][nt][reg] * scale + bias + mv;
      }
      float mx = fmaxf(fmaxf(sc[0], sc[1]), fmaxf(sc[2], sc[3]));
      mx = fmaxf(mx, __shfl_xor(mx, 1));
      mx = fmaxf(mx, __shfl_xor(mx, 2));
      mx = fmaxf(mx, __shfl_xor(mx, 4));
      mx = fmaxf(mx, __shfl_xor(mx, 8));
      float p[4], sum = 0.f;
#pragma unroll
      for (int nt = 0; nt < 4; ++nt) { p[nt] = __expf(sc[nt] - mx); sum += p[nt]; }
      sum += __shfl_xor(sum, 1);
      sum += __shfl_xor(sum, 2);
      sum += __shfl_xor(sum, 4);
      sum += __shfl_xor(sum, 8);
      const float inv = 1.f / sum;
      const int r = mt * 16 + quad * 4 + reg;
#pragma unroll
      for (int nt = 0; nt < 4; ++nt)
        Plds[(wave * 64 + r) * 80 + nt * 16 + l15] = f2bf(p[nt] * inv);
    }
  }

  bf16x8 vf[2][2];
#pragma unroll
  for (int kt = 0; kt < 2; ++kt)
#pragma unroll
    for (int n2 = 0; n2 < 2; ++n2)
#pragma unroll
      for (int j = 0; j < 8; ++j)
        vf[kt][n2][j] =
            base[(size_t)(kt * 32 + quad * 8 + j) * 768 + 512 + h * 32 + n2 * 16 + l15];

  f32x4 O[4][2] = {};
#pragma unroll
  for (int mt = 0; mt < 4; ++mt) {
    const short* pr = &Plds[(wave * 64 + mt * 16 + l15) * 80 + quad * 8];
    const bf16x8 pa0 = *(const bf16x8*)pr;
    const bf16x8 pa1 = *(const bf16x8*)(pr + 32);
#pragma unroll
    for (int n2 = 0; n2 < 2; ++n2) {
      O[mt][n2] = __builtin_amdgcn_mfma_f32_16x16x32_bf16(pa0, vf[0][n2], O[mt][n2], 0, 0, 0);
      O[mt][n2] = __builtin_amdgcn_mfma_f32_16x16x32_bf16(pa1, vf[1][n2], O[mt][n2], 0, 0, 0);
    }
  }
#pragma unroll
  for (int mt = 0; mt < 4; ++mt)
#pragma unroll
    for (int n2 = 0; n2 < 2; ++n2)
#pragma unroll
      for (int reg = 0; reg < 4; ++reg) {
        const int tok = mt * 16 + quad * 4 + reg;
        aout[((size_t)win * 64 + tok) * 256 + h * 32 + n2 * 16 + l15] =
            f2bf(O[mt][n2][reg]);
      }
}

// ---------------------------------------------------------------------------
extern "C" void kernel_launch(void* const* d_in, const int* in_sizes, int n_in,
                              void* d_out, int out_size, void* d_ws,
                              size_t ws_size, hipStream_t stream) {
  const float* x      = (const float*)d_in[0];
  const float* n1g    = (const float*)d_in[1];
  const float* n1b    = (const float*)d_in[2];
  const float* qkv_w  = (const float*)d_in[3];
  const float* qkv_b  = (const float*)d_in[4];
  const float* proj_w = (const float*)d_in[5];
  const float* proj_b = (const float*)d_in[6];
  const float* rpb    = (const float*)d_in[7];
  const float* n2g    = (const float*)d_in[8];
  const float* n2b    = (const float*)d_in[9];
  const float* fc1_w  = (const float*)d_in[10];
  const float* fc1_b  = (const float*)d_in[11];
  const float* fc2_w  = (const float*)d_in[12];
  const float* fc2_b  = (const float*)d_in[13];

  char* ws = (char*)d_ws;
  short* wt_qkv  = (short*)(ws + 0);          //     393,216 B
  short* wt_proj = (short*)(ws + 393216);     //     131,072 B
  short* wt_fc1  = (short*)(ws + 524288);     //     524,288 B
  short* wt_fc2  = (short*)(ws + 1048576);    //     524,288 B
  short* bufS    = (short*)(ws + 1572864);    //  51,380,224 B (xw/ao/yn)
  short* bufL    = (short*)(ws + 52953088);   // 205,520,896 B (qkv/h1)
  // total 258,473,984 B  (round-1 used 361 MB without corruption)
  float* x1      = (float*)d_out;             // x1 lives in d_out (f32)

  transpose_all_k<<<3072, 256, 0, stream>>>(qkv_w, proj_w, fc1_w, fc2_w,
                                            wt_qkv, wt_proj, wt_fc1, wt_fc2);
  ln1_part_k<<<25088, 256, 0, stream>>>(x, n1g, n1b, bufS);
  gemm_k<0><<<dim3(6, 784), 256, 0, stream>>>(bufS, wt_qkv, qkv_b, nullptr,
                                              bufL, 768, 256);
  attn_k<<<3136, 256, 0, stream>>>(bufL, rpb, bufS);
  gemm_k<2><<<dim3(2, 784), 256, 0, stream>>>(bufS, wt_proj, proj_b, x,
                                              x1, 256, 256);
  ln2_k<<<25088, 256, 0, stream>>>(x1, n2g, n2b, bufS);
  gemm_k<1><<<dim3(8, 784), 256, 0, stream>>>(bufS, wt_fc1, fc1_b, nullptr,
                                              bufL, 1024, 256);
  gemm_k<3><<<dim3(2, 784), 256, 0, stream>>>(bufL, wt_fc2, fc2_b, x1,
                                              x1, 256, 1024);
}